// Round 1
// baseline (7833.158 us; speedup 1.0000x reference)
//
#include <hip/hip_runtime.h>
#include <math.h>

#define NLOR 65536
#define NG   128

// butterfly reduce across the 64-lane wave; every lane ends with the sum
__device__ __forceinline__ float wave_sum(float v) {
    v += __shfl_xor(v, 1);
    v += __shfl_xor(v, 2);
    v += __shfl_xor(v, 4);
    v += __shfl_xor(v, 8);
    v += __shfl_xor(v, 16);
    v += __shfl_xor(v, 32);
    return v;
}

// One wave == one LOR. Lane handles planes k=lane and k=lane+64.
// SI/SJ/SK are the z-layout strides for coord0 / coord1 / main-axis coord.
template<int SI, int SJ, int SK>
__global__ __launch_bounds__(256)
void lor_pass(const float* __restrict__ lors,   // [6][NLOR]
              const float* __restrict__ image,  // 128^3, z-layout
              float* __restrict__ bp)           // 128^3 accumulator, z-layout
{
    const int lane = threadIdx.x & 63;
    const int lor  = blockIdx.x * 4 + (threadIdx.x >> 6);

    const float vox   = 214.0f / 128.0f;          // 1.671875
    const float xmin  = -0.5f * 214.0f;           // same for all axes (center 0)
    const float twos2 = (float)(2.0 * (214.0/128.0) * (214.0/128.0) / 3.14159265358979323846);

    const float p1x = lors[0 * NLOR + lor];
    const float p1y = lors[1 * NLOR + lor];
    const float p1z = lors[2 * NLOR + lor];
    const float p2x = lors[3 * NLOR + lor];
    const float p2y = lors[4 * NLOR + lor];
    const float p2z = lors[5 * NLOR + lor];

    const float dx  = p2x - p1x;
    const float dy  = p2y - p1y;
    const float dz0 = p2z - p1z;
    const float L   = sqrtf(dx * dx + dy * dy + dz0 * dz0);
    const float dz  = (fabsf(dz0) < 1e-6f) ? 1e-6f : dz0;
    const float dl  = vox * L / fabsf(dz);

    float wv[18];
    int   fl[18];
    float acc = 0.0f;

#pragma unroll
    for (int h = 0; h < 2; ++h) {
        const int   k  = lane + 64 * h;
        const float zc = xmin + ((float)k + 0.5f) * vox;
        const float t  = (zc - p1z) / dz;
        const float xs = p1x + t * dx;
        const float ys = p1y + t * dy;
        const float fi = (xs - xmin) / vox - 0.5f;
        const float fj = (ys - xmin) / vox - 0.5f;
        const int   i0 = (int)rintf(fi);   // round-half-even == jnp.round
        const int   j0 = (int)rintf(fj);
        const bool  tin = (t >= 0.0f) && (t <= 1.0f);

#pragma unroll
        for (int u = 0; u < 9; ++u) {
            const int oi = u / 3 - 1;
            const int oj = u % 3 - 1;
            const int ii = i0 + oi;
            const int jj = j0 + oj;
            const bool inb = tin && (ii >= 0) && (ii < NG) && (jj >= 0) && (jj < NG);
            const int iic = min(max(ii, 0), NG - 1);
            const int jjc = min(max(jj, 0), NG - 1);
            const float dxv = xmin + ((float)iic + 0.5f) * vox - xs;
            const float dyv = xmin + ((float)jjc + 0.5f) * vox - ys;
            float w = expf(-(dxv * dxv + dyv * dyv) / twos2);
            w = inb ? w : 0.0f;
            const int flat = iic * SI + jjc * SJ + k * SK;
            wv[h * 9 + u] = w;
            fl[h * 9 + u] = flat;
            acc += w * image[flat];
        }
    }

    const float proj = wave_sum(acc) * dl;
    const float cf   = dl / (proj + 1e-8f);

#pragma unroll
    for (int u = 0; u < 18; ++u) {
        if (wv[u] != 0.0f) {
            atomicAdd(&bp[fl[u]], wv[u] * cf);
        }
    }
}

__global__ void finalize_kernel(const float* __restrict__ img,
                                const float* __restrict__ eff,
                                float* __restrict__ out, int n)
{
    const int i = blockIdx.x * blockDim.x + threadIdx.x;
    if (i < n) {
        out[i] = img[i] / (eff[i] + 1e-8f) * out[i];
    }
}

extern "C" void kernel_launch(void* const* d_in, const int* in_sizes, int n_in,
                              void* d_out, int out_size, void* d_ws, size_t ws_size,
                              hipStream_t stream) {
    const float* image = (const float*)d_in[0];
    const float* eff   = (const float*)d_in[1];
    const float* xl    = (const float*)d_in[2];
    const float* yl    = (const float*)d_in[3];
    const float* zl    = (const float*)d_in[4];
    float* out = (float*)d_out;

    hipMemsetAsync(out, 0, (size_t)out_size * sizeof(float), stream);

    dim3 grid(NLOR / 4), block(256);
    // z-lors: coord0->x (stride 16384), coord1->y (128), main->z (1)
    lor_pass<16384, 128, 1><<<grid, block, 0, stream>>>(zl, image, out);
    // x-lors: coord0->z (1), coord1->x (16384), main->y (128)
    lor_pass<1, 16384, 128><<<grid, block, 0, stream>>>(xl, image, out);
    // y-lors: coord0->y (128), coord1->x (16384), main->z (1)
    lor_pass<128, 16384, 1><<<grid, block, 0, stream>>>(yl, image, out);

    const int n = out_size;
    finalize_kernel<<<(n + 255) / 256, 256, 0, stream>>>(image, eff, out, n);
}

// Round 2
// 2513.965 us; speedup vs baseline: 3.1159x; 3.1159x over previous
//
#include <hip/hip_runtime.h>
#include <math.h>

#define NLOR  65536
#define NG    128
#define PLANE (NG * NG)

#define VOX    1.671875f                 /* 214/128 exact */
#define XMIN  (-107.0f)
/* 1 / (2*sigma^2), sigma^2 = vox^2/pi  ->  inv = pi/(2*vox^2) */
#define INV2S2 ((float)(3.14159265358979323846 / (2.0 * (214.0/128.0) * (214.0/128.0))))

__device__ __forceinline__ void lor_geom(const float* __restrict__ lors, int lor,
    float& p1x, float& p1y, float& p1z,
    float& dx, float& dy, float& dz, float& dl)
{
    p1x = lors[0 * NLOR + lor];
    p1y = lors[1 * NLOR + lor];
    p1z = lors[2 * NLOR + lor];
    const float p2x = lors[3 * NLOR + lor];
    const float p2y = lors[4 * NLOR + lor];
    const float p2z = lors[5 * NLOR + lor];
    dx = p2x - p1x; dy = p2y - p1y;
    const float dz0 = p2z - p1z;
    const float L = sqrtf(dx * dx + dy * dy + dz0 * dz0);
    dz = (fabsf(dz0) < 1e-6f) ? 1e-6f : dz0;
    dl = VOX * L / fabsf(dz);
}

// ---------------------------------------------------------------------------
// Generic tiled 3D permute. Output layout is always ((P*128 + Q)*128 + R).
// Input address = P*SP + Q*SQ + R*SR. CONTIG: which of {P(0),Q(1)} has input
// stride 1 (tile-transposed against R so both read and write coalesce).
// ---------------------------------------------------------------------------
template<int SP, int SQ, int SR, int CONTIG, bool ACCUM>
__global__ __launch_bounds__(256)
void permute_k(const float* __restrict__ in, float* __restrict__ out)
{
    __shared__ float tile[32][33];
    const int b  = blockIdx.z;        // non-tiled axis value
    const int c0 = blockIdx.x * 32;   // tile origin along contig axis
    const int r0 = blockIdx.y * 32;   // tile origin along R
    const int tx = threadIdx.x, ty = threadIdx.y;

#pragma unroll
    for (int m = 0; m < 4; ++m) {
        const int C = c0 + tx;
        const int R = r0 + ty + 8 * m;
        const int P = (CONTIG == 0) ? C : b;
        const int Q = (CONTIG == 0) ? b : C;
        tile[ty + 8 * m][tx] = in[P * SP + Q * SQ + R * SR];
    }
    __syncthreads();
#pragma unroll
    for (int m = 0; m < 4; ++m) {
        const int R = r0 + tx;
        const int C = c0 + ty + 8 * m;
        const int P = (CONTIG == 0) ? C : b;
        const int Q = (CONTIG == 0) ? b : C;
        const int o = P * PLANE + Q * NG + R;
        if (ACCUM) out[o] += tile[tx][ty + 8 * m];
        else       out[o]  = tile[tx][ty + 8 * m];
    }
}

// ---------------------------------------------------------------------------
// Phase 1: per-(LOR, plane) projection partials. Image plane staged in LDS.
// 2 workgroups per plane (each half of the LORs). No atomics anywhere.
// ---------------------------------------------------------------------------
__global__ __launch_bounds__(1024)
void plane_proj(const float* __restrict__ lors, const float* __restrict__ imgP,
                float* __restrict__ part)
{
    __shared__ float pl[PLANE];
    const int k    = blockIdx.x >> 1;
    const int half = blockIdx.x & 1;
    const int tid  = threadIdx.x;

    const float4* src = (const float4*)(imgP + k * PLANE);
    float4* dst = (float4*)pl;
    for (int i = tid; i < PLANE / 4; i += 1024) dst[i] = src[i];
    __syncthreads();

    const float zc = XMIN + ((float)k + 0.5f) * VOX;
    const int lo = half * (NLOR / 2), hi = lo + NLOR / 2;
    for (int lor = lo + tid; lor < hi; lor += 1024) {
        float p1x, p1y, p1z, dx, dy, dz, dl;
        lor_geom(lors, lor, p1x, p1y, p1z, dx, dy, dz, dl);
        const float t  = (zc - p1z) / dz;
        const float xs = p1x + t * dx;
        const float ys = p1y + t * dy;
        const float fi = (xs - XMIN) / VOX - 0.5f;
        const float fj = (ys - XMIN) / VOX - 0.5f;
        const int i0 = (int)rintf(fi);
        const int j0 = (int)rintf(fj);
        const bool tin = (t >= 0.0f) && (t <= 1.0f);
        float s = 0.0f;
#pragma unroll
        for (int u = 0; u < 9; ++u) {
            const int oi = u / 3 - 1, oj = u % 3 - 1;
            const int ii = i0 + oi, jj = j0 + oj;
            const bool inb = tin && (ii >= 0) && (ii < NG) && (jj >= 0) && (jj < NG);
            const int iic = min(max(ii, 0), NG - 1);
            const int jjc = min(max(jj, 0), NG - 1);
            const float dxv = XMIN + ((float)iic + 0.5f) * VOX - xs;
            const float dyv = XMIN + ((float)jjc + 0.5f) * VOX - ys;
            float w = __expf(-(dxv * dxv + dyv * dyv) * INV2S2);
            w = inb ? w : 0.0f;
            s += w * pl[iic * NG + jjc];
        }
        part[k * NLOR + lor] = s;
    }
}

// ---------------------------------------------------------------------------
// cf[lor] = dl / (dl * sum_k part + 1e-8)
// ---------------------------------------------------------------------------
__global__ __launch_bounds__(256)
void reduce_cf(const float* __restrict__ lors, const float* __restrict__ part,
               float* __restrict__ cf)
{
    const int lor = blockIdx.x * 256 + threadIdx.x;
    float s = 0.0f;
    for (int k = 0; k < NG; ++k) s += part[k * NLOR + lor];
    float p1x, p1y, p1z, dx, dy, dz, dl;
    lor_geom(lors, lor, p1x, p1y, p1z, dx, dy, dz, dl);
    const float proj = s * dl;
    cf[lor] = dl / (proj + 1e-8f);
}

// ---------------------------------------------------------------------------
// Phase 2: backprojection. One workgroup owns plane k; accumulate via LDS
// atomics; flush with plain float4 stores. No global atomics.
// ---------------------------------------------------------------------------
__global__ __launch_bounds__(1024)
void plane_bp(const float* __restrict__ lors, const float* __restrict__ cf,
              float* __restrict__ bpP)
{
    __shared__ float pl[PLANE];
    const int k   = blockIdx.x;
    const int tid = threadIdx.x;

    const float4 z4 = {0.0f, 0.0f, 0.0f, 0.0f};
    float4* dst = (float4*)pl;
    for (int i = tid; i < PLANE / 4; i += 1024) dst[i] = z4;
    __syncthreads();

    const float zc = XMIN + ((float)k + 0.5f) * VOX;
    for (int lor = tid; lor < NLOR; lor += 1024) {
        float p1x, p1y, p1z, dx, dy, dz, dl;
        lor_geom(lors, lor, p1x, p1y, p1z, dx, dy, dz, dl);
        const float cfv = cf[lor];
        const float t  = (zc - p1z) / dz;
        const float xs = p1x + t * dx;
        const float ys = p1y + t * dy;
        const float fi = (xs - XMIN) / VOX - 0.5f;
        const float fj = (ys - XMIN) / VOX - 0.5f;
        const int i0 = (int)rintf(fi);
        const int j0 = (int)rintf(fj);
        const bool tin = (t >= 0.0f) && (t <= 1.0f);
#pragma unroll
        for (int u = 0; u < 9; ++u) {
            const int oi = u / 3 - 1, oj = u % 3 - 1;
            const int ii = i0 + oi, jj = j0 + oj;
            const bool inb = tin && (ii >= 0) && (ii < NG) && (jj >= 0) && (jj < NG);
            if (inb) {
                const float dxv = XMIN + ((float)ii + 0.5f) * VOX - xs;
                const float dyv = XMIN + ((float)jj + 0.5f) * VOX - ys;
                const float w = __expf(-(dxv * dxv + dyv * dyv) * INV2S2);
                atomicAdd(&pl[ii * NG + jj], w * cfv);
            }
        }
    }
    __syncthreads();

    float4* out4 = (float4*)(bpP + k * PLANE);
    const float4* s4 = (const float4*)pl;
    for (int i = tid; i < PLANE / 4; i += 1024) out4[i] = s4[i];
}

__global__ __launch_bounds__(256)
void finalize_kernel(const float* __restrict__ img, const float* __restrict__ eff,
                     float* __restrict__ out, int n)
{
    const int i = blockIdx.x * blockDim.x + threadIdx.x;
    if (i < n) out[i] = img[i] / (eff[i] + 1e-8f) * out[i];
}

extern "C" void kernel_launch(void* const* d_in, const int* in_sizes, int n_in,
                              void* d_out, int out_size, void* d_ws, size_t ws_size,
                              hipStream_t stream) {
    const float* image = (const float*)d_in[0];
    const float* eff   = (const float*)d_in[1];
    const float* xl    = (const float*)d_in[2];
    const float* yl    = (const float*)d_in[3];
    const float* zl    = (const float*)d_in[4];
    float* out = (float*)d_out;

    char* ws = (char*)d_ws;
    float* imgP = (float*)(ws);                       //  8 MB  [k][ii][jj]
    float* part = (float*)(ws + (size_t)( 8 << 20));  // 32 MB  [k][lor]
    float* bpP  = (float*)(ws + (size_t)(40 << 20));  //  8 MB  [k][ii][jj]
    float* cf   = (float*)(ws + (size_t)(48 << 20));  // 256 KB [lor]

    hipMemsetAsync(out, 0, (size_t)out_size * sizeof(float), stream);

    const dim3 tb(32, 8), tg(4, 4, 128);

    // ---- z pass: (k,ii,jj) = (z,x,y); img strides (z:1, x:16384, y:128)
    permute_k<1, 16384, 128, 0, false><<<tg, tb, 0, stream>>>(image, imgP);
    plane_proj<<<256, 1024, 0, stream>>>(zl, imgP, part);
    reduce_cf<<<256, 256, 0, stream>>>(zl, part, cf);
    plane_bp<<<128, 1024, 0, stream>>>(zl, cf, bpP);
    // back: bpP_z[z][x][y] -> out(x,y,z): in strides (x:128, y:1, z:16384)
    permute_k<128, 1, 16384, 1, true><<<tg, tb, 0, stream>>>(bpP, out);

    // ---- x pass: (k,ii,jj) = (y,z,x); img strides (y:128, z:1, x:16384)
    permute_k<128, 1, 16384, 1, false><<<tg, tb, 0, stream>>>(image, imgP);
    plane_proj<<<256, 1024, 0, stream>>>(xl, imgP, part);
    reduce_cf<<<256, 256, 0, stream>>>(xl, part, cf);
    plane_bp<<<128, 1024, 0, stream>>>(xl, cf, bpP);
    // back: bpP_x[y][z][x] -> out(x,y,z): in strides (x:1, y:16384, z:128)
    permute_k<1, 16384, 128, 0, true><<<tg, tb, 0, stream>>>(bpP, out);

    // ---- y pass: (k,ii,jj) = (z,y,x); img strides (z:1, y:128, x:16384)
    permute_k<1, 128, 16384, 0, false><<<tg, tb, 0, stream>>>(image, imgP);
    plane_proj<<<256, 1024, 0, stream>>>(yl, imgP, part);
    reduce_cf<<<256, 256, 0, stream>>>(yl, part, cf);
    plane_bp<<<128, 1024, 0, stream>>>(yl, cf, bpP);
    // back: bpP_y[z][y][x] -> out(x,y,z): in strides (x:1, y:128, z:16384)
    permute_k<1, 128, 16384, 0, true><<<tg, tb, 0, stream>>>(bpP, out);

    finalize_kernel<<<(out_size + 255) / 256, 256, 0, stream>>>(image, eff, out, out_size);
}

// Round 3
// 1431.694 us; speedup vs baseline: 5.4712x; 1.7559x over previous
//
#include <hip/hip_runtime.h>
#include <math.h>

#define NLOR  65536
#define NG    128
#define PLANE (NG * NG)
#define NSUB  4

#define VOX    1.671875f                 /* 214/128 exact */
#define XMIN  (-107.0f)
/* 1 / (2*sigma^2), sigma^2 = vox^2/pi  ->  inv = pi/(2*vox^2) */
#define INV2S2 ((float)(3.14159265358979323846 / (2.0 * (214.0/128.0) * (214.0/128.0))))

__device__ __forceinline__ void lor_geom(const float* __restrict__ lors, int lor,
    float& p1x, float& p1y, float& p1z,
    float& dx, float& dy, float& dz, float& dl)
{
    p1x = lors[0 * NLOR + lor];
    p1y = lors[1 * NLOR + lor];
    p1z = lors[2 * NLOR + lor];
    const float p2x = lors[3 * NLOR + lor];
    const float p2y = lors[4 * NLOR + lor];
    const float p2z = lors[5 * NLOR + lor];
    dx = p2x - p1x; dy = p2y - p1y;
    const float dz0 = p2z - p1z;
    const float L = sqrtf(dx * dx + dy * dy + dz0 * dz0);
    dz = (fabsf(dz0) < 1e-6f) ? 1e-6f : dz0;
    dl = VOX * L / fabsf(dz);
}

// separable clipped Gaussian row weights along one axis.
// e[o] = w for offset o-1 (0 if that offset is out of bounds), c[o] = clipped idx
__device__ __forceinline__ void axis_w(int c0, float xs, float* e, int* c)
{
#pragma unroll
    for (int o = 0; o < 3; ++o) {
        const int i = c0 + o - 1;
        const int ic = min(max(i, 0), NG - 1);
        const float d = XMIN + ((float)ic + 0.5f) * VOX - xs;
        float w = __expf(-d * d * INV2S2);
        e[o] = (i >= 0 && i < NG) ? w : 0.0f;
        c[o] = ic;
    }
}

// ---------------------------------------------------------------------------
// Generic tiled 3D permute. Output layout is always ((P*128 + Q)*128 + R).
// Input address = P*SP + Q*SQ + R*SR (+ s*NG*PLANE for NSUM sub-buffers,
// summed). CONTIG: which of {P(0),Q(1)} has input stride 1.
// ---------------------------------------------------------------------------
template<int SP, int SQ, int SR, int CONTIG, int NSUM, bool ACCUM>
__global__ __launch_bounds__(256)
void permute_k(const float* __restrict__ in, float* __restrict__ out)
{
    __shared__ float tile[32][33];
    const int b  = blockIdx.z;        // non-tiled axis value
    const int c0 = blockIdx.x * 32;   // tile origin along contig axis
    const int r0 = blockIdx.y * 32;   // tile origin along R
    const int tx = threadIdx.x, ty = threadIdx.y;

#pragma unroll
    for (int m = 0; m < 4; ++m) {
        const int C = c0 + tx;
        const int R = r0 + ty + 8 * m;
        const int P = (CONTIG == 0) ? C : b;
        const int Q = (CONTIG == 0) ? b : C;
        const int a = P * SP + Q * SQ + R * SR;
        float v = 0.0f;
#pragma unroll
        for (int s = 0; s < NSUM; ++s) v += in[a + s * NG * PLANE];
        tile[ty + 8 * m][tx] = v;
    }
    __syncthreads();
#pragma unroll
    for (int m = 0; m < 4; ++m) {
        const int R = r0 + tx;
        const int C = c0 + ty + 8 * m;
        const int P = (CONTIG == 0) ? C : b;
        const int Q = (CONTIG == 0) ? b : C;
        const int o = P * PLANE + Q * NG + R;
        if (ACCUM) out[o] += tile[tx][ty + 8 * m];
        else       out[o]  = tile[tx][ty + 8 * m];
    }
}

// ---------------------------------------------------------------------------
// Phase 1: per-(LOR, plane) projection partials. Image plane staged in LDS.
// 2 workgroups per plane (each half of the LORs). No atomics anywhere.
// ---------------------------------------------------------------------------
__global__ __launch_bounds__(1024)
void plane_proj(const float* __restrict__ lors, const float* __restrict__ imgP,
                float* __restrict__ part)
{
    __shared__ float pl[PLANE];
    const int k    = blockIdx.x >> 1;
    const int half = blockIdx.x & 1;
    const int tid  = threadIdx.x;

    const float4* src = (const float4*)(imgP + k * PLANE);
    float4* dst = (float4*)pl;
    for (int i = tid; i < PLANE / 4; i += 1024) dst[i] = src[i];
    __syncthreads();

    const float zc = XMIN + ((float)k + 0.5f) * VOX;
    const int lo = half * (NLOR / 2), hi = lo + NLOR / 2;
    for (int lor = lo + tid; lor < hi; lor += 1024) {
        float p1x, p1y, p1z, dx, dy, dz, dl;
        lor_geom(lors, lor, p1x, p1y, p1z, dx, dy, dz, dl);
        const float t  = (zc - p1z) / dz;
        const float xs = p1x + t * dx;
        const float ys = p1y + t * dy;
        const int i0 = (int)rintf((xs - XMIN) / VOX - 0.5f);
        const int j0 = (int)rintf((ys - XMIN) / VOX - 0.5f);
        const bool tin = (t >= 0.0f) && (t <= 1.0f);
        float ex[3], ey[3]; int ci[3], cj[3];
        axis_w(i0, xs, ex, ci);
        axis_w(j0, ys, ey, cj);
        float s = 0.0f;
        if (tin) {
#pragma unroll
            for (int a = 0; a < 3; ++a) {
                float r = 0.0f;
#pragma unroll
                for (int bo = 0; bo < 3; ++bo) r += ey[bo] * pl[ci[a] * NG + cj[bo]];
                s += ex[a] * r;
            }
        }
        part[k * NLOR + lor] = s;
    }
}

// ---------------------------------------------------------------------------
// cf[lor] = dl / (dl * sum_k part + 1e-8)
// ---------------------------------------------------------------------------
__global__ __launch_bounds__(256)
void reduce_cf(const float* __restrict__ lors, const float* __restrict__ part,
               float* __restrict__ cf)
{
    const int lor = blockIdx.x * 256 + threadIdx.x;
    float s = 0.0f;
    for (int k = 0; k < NG; ++k) s += part[k * NLOR + lor];
    float p1x, p1y, p1z, dx, dy, dz, dl;
    lor_geom(lors, lor, p1x, p1y, p1z, dx, dy, dz, dl);
    const float proj = s * dl;
    cf[lor] = dl / (proj + 1e-8f);
}

// ---------------------------------------------------------------------------
// Phase 2: backprojection. NSUB blocks per plane, each owning a private LDS
// plane over NLOR/NSUB LORs; flush to its own sub-volume. No global atomics.
// ---------------------------------------------------------------------------
__global__ __launch_bounds__(1024)
void plane_bp(const float* __restrict__ lors, const float* __restrict__ cf,
              float* __restrict__ bpsub)
{
    __shared__ float pl[PLANE];
    const int k   = blockIdx.x >> 2;
    const int sub = blockIdx.x & 3;
    const int tid = threadIdx.x;

    const float4 z4 = {0.0f, 0.0f, 0.0f, 0.0f};
    float4* dst = (float4*)pl;
    for (int i = tid; i < PLANE / 4; i += 1024) dst[i] = z4;
    __syncthreads();

    const float zc = XMIN + ((float)k + 0.5f) * VOX;
    const int lo = sub * (NLOR / NSUB), hi = lo + NLOR / NSUB;
    for (int lor = lo + tid; lor < hi; lor += 1024) {
        const float p1x = lors[0 * NLOR + lor];
        const float p1y = lors[1 * NLOR + lor];
        const float p1z = lors[2 * NLOR + lor];
        const float dx  = lors[3 * NLOR + lor] - p1x;
        const float dy  = lors[4 * NLOR + lor] - p1y;
        float dz = lors[5 * NLOR + lor] - p1z;
        dz = (fabsf(dz) < 1e-6f) ? 1e-6f : dz;
        const float cfv = cf[lor];
        const float t  = (zc - p1z) / dz;
        const float xs = p1x + t * dx;
        const float ys = p1y + t * dy;
        const int i0 = (int)rintf((xs - XMIN) / VOX - 0.5f);
        const int j0 = (int)rintf((ys - XMIN) / VOX - 0.5f);
        const bool tin = (t >= 0.0f) && (t <= 1.0f);
        if (tin) {
            float ex[3], ey[3]; int ci[3], cj[3];
            axis_w(i0, xs, ex, ci);
            axis_w(j0, ys, ey, cj);
#pragma unroll
            for (int a = 0; a < 3; ++a) {
                const float wa = ex[a] * cfv;
                if (wa != 0.0f) {
#pragma unroll
                    for (int bo = 0; bo < 3; ++bo) {
                        const float w = wa * ey[bo];
                        if (w != 0.0f) atomicAdd(&pl[ci[a] * NG + cj[bo]], w);
                    }
                }
            }
        }
    }
    __syncthreads();

    float4* out4 = (float4*)(bpsub + ((size_t)sub * NG + k) * PLANE);
    const float4* s4 = (const float4*)pl;
    for (int i = tid; i < PLANE / 4; i += 1024) out4[i] = s4[i];
}

__global__ __launch_bounds__(256)
void finalize_kernel(const float* __restrict__ img, const float* __restrict__ eff,
                     float* __restrict__ out, int n)
{
    const int i = blockIdx.x * blockDim.x + threadIdx.x;
    if (i < n) out[i] = img[i] / (eff[i] + 1e-8f) * out[i];
}

extern "C" void kernel_launch(void* const* d_in, const int* in_sizes, int n_in,
                              void* d_out, int out_size, void* d_ws, size_t ws_size,
                              hipStream_t stream) {
    const float* image = (const float*)d_in[0];
    const float* eff   = (const float*)d_in[1];
    const float* xl    = (const float*)d_in[2];
    const float* yl    = (const float*)d_in[3];
    const float* zl    = (const float*)d_in[4];
    float* out = (float*)d_out;

    char* ws = (char*)d_ws;
    float* imgP  = (float*)(ws);                       //  8 MB [k][ii][jj]
    float* part  = (float*)(ws + (size_t)( 8 << 20));  // 32 MB [k][lor]   (proj phase)
    float* bpsub = part;                               // 32 MB [sub][k][ii][jj] (bp phase; part is dead by then)
    float* cf    = (float*)(ws + (size_t)(40 << 20));  // 256 KB [lor]

    hipMemsetAsync(out, 0, (size_t)out_size * sizeof(float), stream);

    const dim3 tb(32, 8), tg(4, 4, 128);

    // ---- z pass: (k,ii,jj) = (z,x,y); img strides (z:1, x:16384, y:128)
    permute_k<1, 16384, 128, 0, 1, false><<<tg, tb, 0, stream>>>(image, imgP);
    plane_proj<<<256, 1024, 0, stream>>>(zl, imgP, part);
    reduce_cf<<<256, 256, 0, stream>>>(zl, part, cf);
    plane_bp<<<128 * NSUB, 1024, 0, stream>>>(zl, cf, bpsub);
    // back: bp_z[z][x][y] -> out(x,y,z): in strides (x:128, y:1, z:16384), sum 4 subs
    permute_k<128, 1, 16384, 1, NSUB, true><<<tg, tb, 0, stream>>>(bpsub, out);

    // ---- x pass: (k,ii,jj) = (y,z,x); img strides (y:128, z:1, x:16384)
    permute_k<128, 1, 16384, 1, 1, false><<<tg, tb, 0, stream>>>(image, imgP);
    plane_proj<<<256, 1024, 0, stream>>>(xl, imgP, part);
    reduce_cf<<<256, 256, 0, stream>>>(xl, part, cf);
    plane_bp<<<128 * NSUB, 1024, 0, stream>>>(xl, cf, bpsub);
    // back: bp_x[y][z][x] -> out(x,y,z): in strides (x:1, y:16384, z:128), sum 4 subs
    permute_k<1, 16384, 128, 0, NSUB, true><<<tg, tb, 0, stream>>>(bpsub, out);

    // ---- y pass: (k,ii,jj) = (z,y,x); img strides (z:1, y:128, x:16384)
    permute_k<1, 128, 16384, 0, 1, false><<<tg, tb, 0, stream>>>(image, imgP);
    plane_proj<<<256, 1024, 0, stream>>>(yl, imgP, part);
    reduce_cf<<<256, 256, 0, stream>>>(yl, part, cf);
    plane_bp<<<128 * NSUB, 1024, 0, stream>>>(yl, cf, bpsub);
    // back: bp_y[z][y][x] -> out(x,y,z): in strides (x:1, y:128, z:16384), sum 4 subs
    permute_k<1, 128, 16384, 0, NSUB, true><<<tg, tb, 0, stream>>>(bpsub, out);

    finalize_kernel<<<(out_size + 255) / 256, 256, 0, stream>>>(image, eff, out, out_size);
}